// Round 17
// baseline (288.039 us; speedup 1.0000x reference)
//
#include <hip/hip_runtime.h>

// VanillaRNN: B=4096, T=1024, I=3, H=32, O=2
// out[b,t,j] = h_t[j];  h_t = tanh(x_t @ W_ih^T + b_ih + b_hh + h_{t-1} @ W_hh^T)
// h_n[b,o] = h_T @ W_fc^T + b_fc
//
// R15 = R13b body VERBATIM (f16-packed dpp ring + fdot2, exp2-tanh,
// wave-internal LDS x-staging, nontemporal f2 stores) with ONE structural
// change: 2 batches/wave in lanes 0-31, lanes 32-63 exec-masked off at
// entry -> 2048 waves = 2 waves/SIMD.
// Theory: at 1 wave/SIMD wall/step ~ 4cyc*instr + 130 (R14 null killed
// dep-distance; single-wave issue cadence + unfillable stalls). Two waves
// interleave issue on the SIMD and hide each other's stalls.

typedef float  f2 __attribute__((ext_vector_type(2)));
typedef _Float16 h2 __attribute__((ext_vector_type(2)));

#define RNN_B 4096
#define RNN_T 1024
#define RNN_H 32
#define GROUPS 8              // batches per block (2 per wave, lanes 0-31)
#define BLOCK 256
#define DEPTH 4               // steps per staging block
#define NBLK (RNN_T / DEPTH)  // 256

#define SCALE 2.8853900817779268f   // 2*log2(e)

template <int M>
__device__ __forceinline__ h2 rotm16(h2 v) {
    // DPP row_ror:M — lane i reads lane (i-M)&15 within its 16-lane row.
    int iv = __builtin_bit_cast(int, v);
    iv = __builtin_amdgcn_mov_dpp(iv, 0x120 | M, 0xf, 0xf, true);
    return __builtin_bit_cast(h2, iv);
}

__global__ __launch_bounds__(BLOCK, 1) void vanilla_rnn_kernel(
    const float* __restrict__ x,     // [B,T,3]
    const float* __restrict__ W_ih,  // [32,3]
    const float* __restrict__ b_ih,  // [32]
    const float* __restrict__ W_hh,  // [32,32]
    const float* __restrict__ b_hh,  // [32]
    const float* __restrict__ W_fc,  // [2,32]
    const float* __restrict__ b_fc,  // [2]
    float* __restrict__ out,         // [B,T,32]
    float* __restrict__ hn_out)      // [B,2]
{
    const int tid  = threadIdx.x;
    const int lane = tid & 63;
    if (lane >= 32) return;            // half-populated wave: 2 batches/wave

    const int wv  = tid >> 6;          // wave within block (0..3)
    const int gw  = (lane >> 4) & 1;   // group within wave (0..1)
    const int p   = lane & 15;         // pair position within 16-lane row
    const int g   = wv * 2 + gw;       // group within block (0..7)
    const int b   = blockIdx.x * GROUPS + g;
    const int j0  = 2 * p;
    const int j1  = 2 * p + 1;

    __shared__ float hs[GROUPS][32];                 // epilogue only
    __shared__ __align__(16) float xs4[4][2][2][12]; // [wave][slot][gw][12]

    // loader role: lanes 0..23 of each wave stream 1 dword per block
    const bool loader = lane < 24;
    const int  lg     = lane / 12;     // group-in-wave it loads for
    const int  fr     = lane % 12;     // float index within a 12-float block
    const float* lsrc = x + (size_t)(blockIdx.x * GROUPS + wv * 2 + lg) * (RNN_T * 3) + fr;

    // W_hh rows j0,j1 in rotation order (pair q=(p-m)&15), pre-scaled, f16.
    h2 Wa[16], Wb[16];
#pragma unroll
    for (int m = 0; m < 16; ++m) {
        const int q = (p - m) & 15;
        Wa[m].x = (_Float16)(W_hh[j0 * 32 + 2 * q]     * SCALE);
        Wa[m].y = (_Float16)(W_hh[j0 * 32 + 2 * q + 1] * SCALE);
        Wb[m].x = (_Float16)(W_hh[j1 * 32 + 2 * q]     * SCALE);
        Wb[m].y = (_Float16)(W_hh[j1 * 32 + 2 * q + 1] * SCALE);
    }

    // x-projection constants (.x -> j0, .y -> j1), pre-scaled (f32)
    f2 wi0, wi1, wi2, bs;
    wi0.x = W_ih[j0 * 3 + 0] * SCALE;  wi0.y = W_ih[j1 * 3 + 0] * SCALE;
    wi1.x = W_ih[j0 * 3 + 1] * SCALE;  wi1.y = W_ih[j1 * 3 + 1] * SCALE;
    wi2.x = W_ih[j0 * 3 + 2] * SCALE;  wi2.y = W_ih[j1 * 3 + 2] * SCALE;
    bs.x  = (b_ih[j0] + b_hh[j0]) * SCALE;
    bs.y  = (b_ih[j1] + b_hh[j1]) * SCALE;

    float* ob = out + (size_t)b * RNN_T * RNN_H;

    // prologue: slots <- blocks 0,1; regs <- blocks 2,3 (all wave-internal)
    float xregA = 0.0f, xregB = 0.0f;
    if (loader) {
        const float d0 = lsrc[0];
        const float d1 = lsrc[12];
        xregA = lsrc[24];
        xregB = lsrc[36];
        xs4[wv][0][lg][fr] = d0;
        xs4[wv][1][lg][fr] = d1;
    }

    float hj0 = 0.0f, hj1 = 0.0f;
    h2 hp0 = (h2){(_Float16)0.0f, (_Float16)0.0f};   // packed (h[j0],h[j1])

#define ROT_STEP(M)                                                \
            {                                                      \
                const h2 r = rotm16<M>(hp0);                       \
                a0 = __builtin_amdgcn_fdot2(r, Wa[M], a0, false);  \
                b0 = __builtin_amdgcn_fdot2(r, Wb[M], b0, false);  \
            }

#define BLOCK_BODY(SLOT, XREG, KB)                                            \
    {                                                                         \
        const float4* sp = reinterpret_cast<const float4*>(&xs4[wv][SLOT][gw][0]); \
        const float4 xq0 = sp[0];                                             \
        const float4 xq1 = sp[1];                                             \
        const float4 xq2 = sp[2];                                             \
        if (loader) {                                                         \
            xs4[wv][SLOT][lg][fr] = XREG;          /* data for KB+2 */        \
            const int kf = ((KB) + 4 < NBLK) ? (KB) + 4 : NBLK - 1;           \
            XREG = lsrc[(size_t)kf * 12];          /* data for KB+4 */        \
        }                                                                     \
        __builtin_amdgcn_sched_barrier(0);                                    \
        const float xv[12] = {xq0.x, xq0.y, xq0.z, xq0.w,                     \
                              xq1.x, xq1.y, xq1.z, xq1.w,                     \
                              xq2.x, xq2.y, xq2.z, xq2.w};                    \
        /* per-block x-projection precompute (h-independent) */               \
        f2 xp[DEPTH];                                                         \
        _Pragma("unroll")                                                     \
        for (int d = 0; d < DEPTH; ++d) {                                     \
            f2 v = bs;                                                        \
            v = __builtin_elementwise_fma(wi0, (f2){xv[d*3+0], xv[d*3+0]}, v);\
            v = __builtin_elementwise_fma(wi1, (f2){xv[d*3+1], xv[d*3+1]}, v);\
            v = __builtin_elementwise_fma(wi2, (f2){xv[d*3+2], xv[d*3+2]}, v);\
            xp[d] = v;                                                        \
        }                                                                     \
        _Pragma("unroll")                                                     \
        for (int d = 0; d < DEPTH; ++d) {                                     \
            float a0 = xp[d].x;                                               \
            float b0 = xp[d].y;                                               \
            a0 = __builtin_amdgcn_fdot2(hp0, Wa[0], a0, false);               \
            b0 = __builtin_amdgcn_fdot2(hp0, Wb[0], b0, false);               \
            ROT_STEP(1)  ROT_STEP(2)  ROT_STEP(3)  ROT_STEP(4)                \
            ROT_STEP(5)  ROT_STEP(6)  ROT_STEP(7)  ROT_STEP(8)                \
            ROT_STEP(9)  ROT_STEP(10) ROT_STEP(11) ROT_STEP(12)               \
            ROT_STEP(13) ROT_STEP(14) ROT_STEP(15)                            \
            /* tanh(z) = 1 - 2/(exp2(2*log2e*z)+1); inf-safe */               \
            const float tha = fmaf(-2.0f, __builtin_amdgcn_rcpf(exp2f(a0) + 1.0f), 1.0f); \
            const float thb = fmaf(-2.0f, __builtin_amdgcn_rcpf(exp2f(b0) + 1.0f), 1.0f); \
            f2 st; st.x = tha; st.y = thb;                                    \
            __builtin_nontemporal_store(                                      \
                st, reinterpret_cast<f2*>(ob + (size_t)((KB) * DEPTH + d) * RNN_H) + p); \
            hp0 = __builtin_bit_cast(h2, __builtin_amdgcn_cvt_pkrtz(tha, thb)); \
            hj0 = tha; hj1 = thb;                                             \
        }                                                                     \
    }

    for (int k = 0; k < NBLK; k += 2) {
        BLOCK_BODY(0, xregA, k)
        BLOCK_BODY(1, xregB, k + 1)
    }

#undef ROT_STEP
#undef BLOCK_BODY

    // h_n = h_T @ W_fc^T + b_fc  (16-lane group is wave-internal, no barrier)
    hs[g][j0] = hj0;
    hs[g][j1] = hj1;
    if (p < 2) {
        float acc = b_fc[p];
#pragma unroll
        for (int k = 0; k < 32; ++k) acc = fmaf(W_fc[p * 32 + k], hs[g][k], acc);
        hn_out[(size_t)b * 2 + p] = acc;
    }
}

extern "C" void kernel_launch(void* const* d_in, const int* in_sizes, int n_in,
                              void* d_out, int out_size, void* d_ws, size_t ws_size,
                              hipStream_t stream) {
    const float* x    = (const float*)d_in[0];
    const float* W_ih = (const float*)d_in[1];
    const float* b_ih = (const float*)d_in[2];
    const float* W_hh = (const float*)d_in[3];
    const float* b_hh = (const float*)d_in[4];
    const float* W_fc = (const float*)d_in[5];
    const float* b_fc = (const float*)d_in[6];

    float* out    = (float*)d_out;                                   // [B,T,H]
    float* hn_out = out + (size_t)RNN_B * RNN_T * RNN_H;             // [B,2]

    const int grid = RNN_B / GROUPS;  // 512 blocks = 2048 waves = 2/SIMD
    vanilla_rnn_kernel<<<grid, BLOCK, 0, stream>>>(
        x, W_ih, b_ih, W_hh, b_hh, W_fc, b_fc, out, hn_out);
}

// Round 18
// 214.369 us; speedup vs baseline: 1.3437x; 1.3437x over previous
//
#include <hip/hip_runtime.h>

// VanillaRNN: B=4096, T=1024, I=3, H=32, O=2
// out[b,t,j] = h_t[j];  h_t = tanh(x_t @ W_ih^T + b_ih + b_hh + h_{t-1} @ W_hh^T)
// h_n[b,o] = h_T @ W_fc^T + b_fc
//
// R16 = R6 structure (one batch across split 32-lane set: lane owns ONE
// output j = p + 16*hi; 2 batches/wave via q=(lane>>4)&1; FULL waves;
// 2048 waves = 2/SIMD) + R13b f16 machinery (h2-packed DPP ring + fdot2,
// exp2-tanh, wave-internal LDS x-staging, nontemporal stores).
// Exchange per step: 1 permlane32_swap (R6-verified) + 1 cvt_pkrtz packs
// (H[p], H[p+16]) into one h2; W pairs (W[j][k], W[j][k+16]), k=(p-m)&15;
// 15 dpp + 16 fdot2 per lane. ~45 instr/wave/step, ~90/SIMD.
// Model (R15 diagnostic): per-wave ~5-6 cyc/instr alone; two FULL waves
// interleave to ~3 (R2/R6 measured); half-waves don't (R15, 1.71x regress).

typedef float  f2 __attribute__((ext_vector_type(2)));
typedef _Float16 h2 __attribute__((ext_vector_type(2)));
typedef int    i2v __attribute__((ext_vector_type(2)));

#define RNN_B 4096
#define RNN_T 1024
#define RNN_H 32
#define GROUPS 8              // batches per block (4 waves x 2)
#define BLOCK 256
#define DEPTH 4               // steps per staging block
#define NBLK (RNN_T / DEPTH)  // 256

#define SCALE 2.8853900817779268f   // 2*log2(e)

template <int M>
__device__ __forceinline__ h2 rotm16(h2 v) {
    // DPP row_ror:M — lane i reads lane (i-M)&15 within its 16-lane row.
    int iv = __builtin_bit_cast(int, v);
    iv = __builtin_amdgcn_mov_dpp(iv, 0x120 | M, 0xf, 0xf, true);
    return __builtin_bit_cast(h2, iv);
}

__global__ __launch_bounds__(BLOCK, 2) void vanilla_rnn_kernel(
    const float* __restrict__ x,     // [B,T,3]
    const float* __restrict__ W_ih,  // [32,3]
    const float* __restrict__ b_ih,  // [32]
    const float* __restrict__ W_hh,  // [32,32]
    const float* __restrict__ b_hh,  // [32]
    const float* __restrict__ W_fc,  // [2,32]
    const float* __restrict__ b_fc,  // [2]
    float* __restrict__ out,         // [B,T,32]
    float* __restrict__ hn_out)      // [B,2]
{
    const int tid  = threadIdx.x;
    const int lane = tid & 63;
    const int wv   = tid >> 6;          // wave within block (0..3)
    const int p    = lane & 15;         // position within 16-lane row
    const int q    = (lane >> 4) & 1;   // batch within wave (0..1)
    const int hi   = lane >> 5;         // 0: j=p, 1: j=p+16
    const int j    = p + 16 * hi;
    const int g    = wv * 2 + q;        // group within block (0..7)
    const int b    = blockIdx.x * GROUPS + g;

    __shared__ float hs[GROUPS][32];                 // epilogue only
    __shared__ __align__(16) float xs4[4][2][2][12]; // [wave][slot][q][12]

    // loader role: lanes 0..23 of each wave stream 1 dword per block
    const bool loader = lane < 24;
    const int  lg     = lane / 12;      // batch-in-wave it loads for
    const int  fr     = lane % 12;      // float index within a 12-float block
    const float* lsrc = x + (size_t)(blockIdx.x * GROUPS + wv * 2 + lg) * (RNN_T * 3) + fr;

    // W_hh row j as (k, k+16) pairs in rotation order (k=(p-m)&15), f16.
    h2 Wp[16];
#pragma unroll
    for (int m = 0; m < 16; ++m) {
        const int ka = (p - m) & 15;
        Wp[m].x = (_Float16)(W_hh[j * 32 + ka]      * SCALE);
        Wp[m].y = (_Float16)(W_hh[j * 32 + ka + 16] * SCALE);
    }

    // x-projection constants for own j, pre-scaled (f32)
    const float wi0 = W_ih[j * 3 + 0] * SCALE;
    const float wi1 = W_ih[j * 3 + 1] * SCALE;
    const float wi2 = W_ih[j * 3 + 2] * SCALE;
    const float bs  = (b_ih[j] + b_hh[j]) * SCALE;

    float* ob = out + (size_t)b * RNN_T * RNN_H;

    // prologue: slots <- blocks 0,1; regs <- blocks 2,3 (all wave-internal)
    float xregA = 0.0f, xregB = 0.0f;
    if (loader) {
        const float d0 = lsrc[0];
        const float d1 = lsrc[12];
        xregA = lsrc[24];
        xregB = lsrc[36];
        xs4[wv][0][lg][fr] = d0;
        xs4[wv][1][lg][fr] = d1;
    }

    float hj = 0.0f;   // own H[j]

#define ROT_STEP(M)                                                \
            {                                                      \
                const h2 r = rotm16<M>(hp0);                       \
                acc = __builtin_amdgcn_fdot2(r, Wp[M], acc, false); \
            }

#define BLOCK_BODY(SLOT, XREG, KB)                                            \
    {                                                                         \
        const float4* sp = reinterpret_cast<const float4*>(&xs4[wv][SLOT][q][0]); \
        const float4 xq0 = sp[0];                                             \
        const float4 xq1 = sp[1];                                             \
        const float4 xq2 = sp[2];                                             \
        if (loader) {                                                         \
            xs4[wv][SLOT][lg][fr] = XREG;          /* data for KB+2 */        \
            const int kf = ((KB) + 4 < NBLK) ? (KB) + 4 : NBLK - 1;           \
            XREG = lsrc[(size_t)kf * 12];          /* data for KB+4 */        \
        }                                                                     \
        __builtin_amdgcn_sched_barrier(0);                                    \
        const float xv[12] = {xq0.x, xq0.y, xq0.z, xq0.w,                     \
                              xq1.x, xq1.y, xq1.z, xq1.w,                     \
                              xq2.x, xq2.y, xq2.z, xq2.w};                    \
        /* per-block x-projection precompute (h-independent) */               \
        float xp[DEPTH];                                                      \
        _Pragma("unroll")                                                     \
        for (int d = 0; d < DEPTH; ++d) {                                     \
            float v = fmaf(wi0, xv[d*3+0], bs);                               \
            v = fmaf(wi1, xv[d*3+1], v);                                      \
            v = fmaf(wi2, xv[d*3+2], v);                                      \
            xp[d] = v;                                                        \
        }                                                                     \
        _Pragma("unroll")                                                     \
        for (int d = 0; d < DEPTH; ++d) {                                     \
            /* pack (H[p], H[p+16]) of own batch into one h2 */               \
            const i2v r = __builtin_amdgcn_permlane32_swap(                   \
                __float_as_int(hj), __float_as_int(hj), false, false);        \
            h2 hp0 = __builtin_bit_cast(h2, __builtin_amdgcn_cvt_pkrtz(       \
                __int_as_float(r.x), __int_as_float(r.y)));                   \
            float acc = xp[d];                                                \
            acc = __builtin_amdgcn_fdot2(hp0, Wp[0], acc, false);             \
            ROT_STEP(1)  ROT_STEP(2)  ROT_STEP(3)  ROT_STEP(4)               \
            ROT_STEP(5)  ROT_STEP(6)  ROT_STEP(7)  ROT_STEP(8)               \
            ROT_STEP(9)  ROT_STEP(10) ROT_STEP(11) ROT_STEP(12)              \
            ROT_STEP(13) ROT_STEP(14) ROT_STEP(15)                            \
            /* tanh(z) = 1 - 2/(exp2(2*log2e*z)+1); inf-safe */               \
            const float th = fmaf(-2.0f, __builtin_amdgcn_rcpf(exp2f(acc) + 1.0f), 1.0f); \
            __builtin_nontemporal_store(th, &ob[(size_t)((KB) * DEPTH + d) * RNN_H + j]); \
            hj = th;                                                          \
        }                                                                     \
    }

    for (int k = 0; k < NBLK; k += 2) {
        BLOCK_BODY(0, xregA, k)
        BLOCK_BODY(1, xregB, k + 1)
    }

#undef ROT_STEP
#undef BLOCK_BODY

    // h_n = h_T @ W_fc^T + b_fc  (batch's 32 lanes are wave-internal)
    hs[g][j] = hj;
    if (hi == 0 && p < 2) {
        float acc = b_fc[p];
#pragma unroll
        for (int k = 0; k < 32; ++k) acc = fmaf(W_fc[p * 32 + k], hs[g][k], acc);
        hn_out[(size_t)b * 2 + p] = acc;
    }
}

extern "C" void kernel_launch(void* const* d_in, const int* in_sizes, int n_in,
                              void* d_out, int out_size, void* d_ws, size_t ws_size,
                              hipStream_t stream) {
    const float* x    = (const float*)d_in[0];
    const float* W_ih = (const float*)d_in[1];
    const float* b_ih = (const float*)d_in[2];
    const float* W_hh = (const float*)d_in[3];
    const float* b_hh = (const float*)d_in[4];
    const float* W_fc = (const float*)d_in[5];
    const float* b_fc = (const float*)d_in[6];

    float* out    = (float*)d_out;                                   // [B,T,H]
    float* hn_out = out + (size_t)RNN_B * RNN_T * RNN_H;             // [B,2]

    const int grid = RNN_B / GROUPS;  // 512 blocks = 2048 full waves = 2/SIMD
    vanilla_rnn_kernel<<<grid, BLOCK, 0, stream>>>(
        x, W_ih, b_ih, W_hh, b_hh, W_fc, b_fc, out, hn_out);
}

// Round 19
// 181.587 us; speedup vs baseline: 1.5862x; 1.1805x over previous
//
#include <hip/hip_runtime.h>

// VanillaRNN: B=4096, T=1024, I=3, H=32, O=2
// out[b,t,j] = h_t[j];  h_t = tanh(x_t @ W_ih^T + b_ih + b_hh + h_{t-1} @ W_hh^T)
// h_n[b,o] = h_T @ W_fc^T + b_fc
//
// R17 = R13b (wave-internal LDS x-staging, 16 lanes/batch, lane owns
// j=2p,2p+1, f16-packed dpp ring, exp2-tanh, nontemporal f2 stores,
// 1 wave/SIMD) with ONE change: the 32 v_dot2_f32_f16 MACs are replaced by
// 32 v_pk_fma_f16 (packed f16 FMA, hypothesized full-rate vs slow dot2).
// Accumulate in packed f16, TWO h2 accs per output (8 terms/slot).
// Precision guard: W stored UNSCALED (|W|<=0.18 -> partials <=1.5, f16 err
// ~0.002); the 2*log2e scale moves into the final reduction:
//   y = fdot2(a0,(S,S), fdot2(a1,(S,S), xp_scaled))   (only 4 fdot2/step)
// Theory: effective rate is ~5-6 cyc/instr across ALL configs (R13b 6.1,
// R15 5.3, R16 5.2) -> the dot2/pk_f32 ops themselves are slow; scalar
// f32 (R2) ran ~2.7. pk_fma_f16 should restore full rate at same count.

typedef float  f2 __attribute__((ext_vector_type(2)));
typedef _Float16 h2 __attribute__((ext_vector_type(2)));

#define RNN_B 4096
#define RNN_T 1024
#define RNN_H 32
#define GROUPS 16             // batches per block (16-lane groups)
#define BLOCK 256
#define DEPTH 4               // steps per staging block
#define NBLK (RNN_T / DEPTH)  // 256

#define SCALE 2.8853900817779268f   // 2*log2(e)

template <int M>
__device__ __forceinline__ h2 rotm16(h2 v) {
    // DPP row_ror:M — lane i reads lane (i-M)&15 within its 16-lane row.
    int iv = __builtin_bit_cast(int, v);
    iv = __builtin_amdgcn_mov_dpp(iv, 0x120 | M, 0xf, 0xf, true);
    return __builtin_bit_cast(h2, iv);
}

__global__ __launch_bounds__(BLOCK, 1) void vanilla_rnn_kernel(
    const float* __restrict__ x,     // [B,T,3]
    const float* __restrict__ W_ih,  // [32,3]
    const float* __restrict__ b_ih,  // [32]
    const float* __restrict__ W_hh,  // [32,32]
    const float* __restrict__ b_hh,  // [32]
    const float* __restrict__ W_fc,  // [2,32]
    const float* __restrict__ b_fc,  // [2]
    float* __restrict__ out,         // [B,T,32]
    float* __restrict__ hn_out)      // [B,2]
{
    const int tid = threadIdx.x;
    const int g   = tid >> 4;          // group within block (0..15)
    const int p   = tid & 15;          // pair position within 16-lane row
    const int wv  = tid >> 6;          // wave within block (0..3)
    const int gw  = (tid >> 4) & 3;    // group within wave (0..3)
    const int b   = blockIdx.x * GROUPS + g;
    const int j0  = 2 * p;
    const int j1  = 2 * p + 1;

    __shared__ float hs[GROUPS][32];                  // epilogue only
    __shared__ __align__(16) float xs4[4][2][4][12];  // [wave][slot][gw][12]

    // loader role: lanes 0..47 of each wave stream 1 dword per block
    const int  lw     = tid & 63;
    const bool loader = lw < 48;
    const int  lg     = lw / 12;       // group-in-wave it loads for
    const int  fr     = lw % 12;       // float index within a 12-float block
    const float* lsrc = x + (size_t)(blockIdx.x * GROUPS + wv * 4 + lg) * (RNN_T * 3) + fr;

    // W_hh rows j0,j1 in rotation order (pair q=(p-m)&15), UNSCALED, f16.
    h2 Wa[16], Wb[16];
#pragma unroll
    for (int m = 0; m < 16; ++m) {
        const int q = (p - m) & 15;
        Wa[m].x = (_Float16)W_hh[j0 * 32 + 2 * q];
        Wa[m].y = (_Float16)W_hh[j0 * 32 + 2 * q + 1];
        Wb[m].x = (_Float16)W_hh[j1 * 32 + 2 * q];
        Wb[m].y = (_Float16)W_hh[j1 * 32 + 2 * q + 1];
    }
    const h2 SS = {(_Float16)SCALE, (_Float16)SCALE};

    // x-projection constants (.x -> j0, .y -> j1), pre-scaled (f32)
    f2 wi0, wi1, wi2, bs;
    wi0.x = W_ih[j0 * 3 + 0] * SCALE;  wi0.y = W_ih[j1 * 3 + 0] * SCALE;
    wi1.x = W_ih[j0 * 3 + 1] * SCALE;  wi1.y = W_ih[j1 * 3 + 1] * SCALE;
    wi2.x = W_ih[j0 * 3 + 2] * SCALE;  wi2.y = W_ih[j1 * 3 + 2] * SCALE;
    bs.x  = (b_ih[j0] + b_hh[j0]) * SCALE;
    bs.y  = (b_ih[j1] + b_hh[j1]) * SCALE;

    float* ob = out + (size_t)b * RNN_T * RNN_H;

    // prologue: slots <- blocks 0,1; regs <- blocks 2,3 (all wave-internal)
    float xregA = 0.0f, xregB = 0.0f;
    if (loader) {
        const float d0 = lsrc[0];
        const float d1 = lsrc[12];
        xregA = lsrc[24];
        xregB = lsrc[36];
        xs4[wv][0][lg][fr] = d0;
        xs4[wv][1][lg][fr] = d1;
    }

    float hj0 = 0.0f, hj1 = 0.0f;
    h2 hp0 = (h2){(_Float16)0.0f, (_Float16)0.0f};   // packed (h[j0],h[j1])

#define ROT_STEP(M, AA, BB)                                        \
            {                                                      \
                const h2 r = rotm16<M>(hp0);                       \
                AA = __builtin_elementwise_fma(r, Wa[M], AA);      \
                BB = __builtin_elementwise_fma(r, Wb[M], BB);      \
            }

#define BLOCK_BODY(SLOT, XREG, KB)                                            \
    {                                                                         \
        const float4* sp = reinterpret_cast<const float4*>(&xs4[wv][SLOT][gw][0]); \
        const float4 xq0 = sp[0];                                             \
        const float4 xq1 = sp[1];                                             \
        const float4 xq2 = sp[2];                                             \
        if (loader) {                                                         \
            xs4[wv][SLOT][lg][fr] = XREG;          /* data for KB+2 */        \
            const int kf = ((KB) + 4 < NBLK) ? (KB) + 4 : NBLK - 1;           \
            XREG = lsrc[(size_t)kf * 12];          /* data for KB+4 */        \
        }                                                                     \
        __builtin_amdgcn_sched_barrier(0);                                    \
        const float xv[12] = {xq0.x, xq0.y, xq0.z, xq0.w,                     \
                              xq1.x, xq1.y, xq1.z, xq1.w,                     \
                              xq2.x, xq2.y, xq2.z, xq2.w};                    \
        /* per-block x-projection precompute (h-independent) */               \
        f2 xp[DEPTH];                                                         \
        _Pragma("unroll")                                                     \
        for (int d = 0; d < DEPTH; ++d) {                                     \
            f2 v = bs;                                                        \
            v = __builtin_elementwise_fma(wi0, (f2){xv[d*3+0], xv[d*3+0]}, v);\
            v = __builtin_elementwise_fma(wi1, (f2){xv[d*3+1], xv[d*3+1]}, v);\
            v = __builtin_elementwise_fma(wi2, (f2){xv[d*3+2], xv[d*3+2]}, v);\
            xp[d] = v;                                                        \
        }                                                                     \
        _Pragma("unroll")                                                     \
        for (int d = 0; d < DEPTH; ++d) {                                     \
            h2 a0 = {(_Float16)0.0f, (_Float16)0.0f};                         \
            h2 a1 = {(_Float16)0.0f, (_Float16)0.0f};                         \
            h2 b0 = {(_Float16)0.0f, (_Float16)0.0f};                         \
            h2 b1 = {(_Float16)0.0f, (_Float16)0.0f};                         \
            a0 = __builtin_elementwise_fma(hp0, Wa[0], a0);                   \
            b0 = __builtin_elementwise_fma(hp0, Wb[0], b0);                   \
            ROT_STEP(1,  a1, b1)  ROT_STEP(2,  a0, b0)                        \
            ROT_STEP(3,  a1, b1)  ROT_STEP(4,  a0, b0)                        \
            ROT_STEP(5,  a1, b1)  ROT_STEP(6,  a0, b0)                        \
            ROT_STEP(7,  a1, b1)  ROT_STEP(8,  a0, b0)                        \
            ROT_STEP(9,  a1, b1)  ROT_STEP(10, a0, b0)                        \
            ROT_STEP(11, a1, b1)  ROT_STEP(12, a0, b0)                        \
            ROT_STEP(13, a1, b1)  ROT_STEP(14, a0, b0)                        \
            ROT_STEP(15, a1, b1)                                              \
            /* y = SCALE*(hW) + xp  via two chained fdot2 with (S,S) */       \
            const float ya = __builtin_amdgcn_fdot2(a0, SS,                   \
                               __builtin_amdgcn_fdot2(a1, SS, xp[d].x, false), false); \
            const float yb = __builtin_amdgcn_fdot2(b0, SS,                   \
                               __builtin_amdgcn_fdot2(b1, SS, xp[d].y, false), false); \
            /* tanh(z) = 1 - 2/(exp2(2*log2e*z)+1); inf-safe */               \
            const float tha = fmaf(-2.0f, __builtin_amdgcn_rcpf(exp2f(ya) + 1.0f), 1.0f); \
            const float thb = fmaf(-2.0f, __builtin_amdgcn_rcpf(exp2f(yb) + 1.0f), 1.0f); \
            f2 st; st.x = tha; st.y = thb;                                    \
            __builtin_nontemporal_store(                                      \
                st, reinterpret_cast<f2*>(ob + (size_t)((KB) * DEPTH + d) * RNN_H) + p); \
            hp0 = __builtin_bit_cast(h2, __builtin_amdgcn_cvt_pkrtz(tha, thb)); \
            hj0 = tha; hj1 = thb;                                             \
        }                                                                     \
    }

    for (int k = 0; k < NBLK; k += 2) {
        BLOCK_BODY(0, xregA, k)
        BLOCK_BODY(1, xregB, k + 1)
    }

#undef ROT_STEP
#undef BLOCK_BODY

    // h_n = h_T @ W_fc^T + b_fc  (16-lane group is wave-internal, no barrier)
    hs[g][j0] = hj0;
    hs[g][j1] = hj1;
    if (p < 2) {
        float acc = b_fc[p];
#pragma unroll
        for (int k = 0; k < 32; ++k) acc = fmaf(W_fc[p * 32 + k], hs[g][k], acc);
        hn_out[(size_t)b * 2 + p] = acc;
    }
}

extern "C" void kernel_launch(void* const* d_in, const int* in_sizes, int n_in,
                              void* d_out, int out_size, void* d_ws, size_t ws_size,
                              hipStream_t stream) {
    const float* x    = (const float*)d_in[0];
    const float* W_ih = (const float*)d_in[1];
    const float* b_ih = (const float*)d_in[2];
    const float* W_hh = (const float*)d_in[3];
    const float* b_hh = (const float*)d_in[4];
    const float* W_fc = (const float*)d_in[5];
    const float* b_fc = (const float*)d_in[6];

    float* out    = (float*)d_out;                                   // [B,T,H]
    float* hn_out = out + (size_t)RNN_B * RNN_T * RNN_H;             // [B,2]

    const int grid = RNN_B / GROUPS;  // 256 blocks = 1024 waves = 1/SIMD
    vanilla_rnn_kernel<<<grid, BLOCK, 0, stream>>>(
        x, W_ih, b_ih, W_hh, b_hh, W_fc, b_fc, out, hn_out);
}

// Round 20
// 178.335 us; speedup vs baseline: 1.6152x; 1.0182x over previous
//
#include <hip/hip_runtime.h>

// VanillaRNN: B=4096, T=1024, I=3, H=32, O=2
// out[b,t,j] = h_t[j];  h_t = tanh(x_t @ W_ih^T + b_ih + b_hh + h_{t-1} @ W_hh^T)
// h_n[b,o] = h_T @ W_fc^T + b_fc
//
// R18: NO DPP (cost model from R4b..R17 fits DPP~10cyc, dot/pk~5-6,
// scalar~2-4; the 15-30 DPP/step were 30-40% of every kernel since R3).
// Topology: lane=(batch,j), 32 lanes/batch, 2 batches/wave, 2048 FULL
// waves = 2/SIMD. h lives in LDS as f16:
//   - per step: 4 broadcast ds_read_b128 deliver ALL 32 h (16 h2) to
//     every lane; 16 fdot2 vs W-row pairs in NATURAL order (no perm);
//     tanh; ds_write_b16 own h; scalar nontemporal store.
//   - ~34 instr/step/wave; chain ~220cyc; 2 waves interleave (R2-proven).
// Wave-internal everything (batch's 32 lanes + its 12 loader lanes in the
// same wave) -> no barriers. x staged via R13b's 2-slot LDS ring.

typedef float  f2 __attribute__((ext_vector_type(2)));
typedef _Float16 h2 __attribute__((ext_vector_type(2)));

#define RNN_B 4096
#define RNN_T 1024
#define RNN_H 32
#define GROUPS 8              // batches per block (4 waves x 2)
#define BLOCK 256
#define DEPTH 4               // steps per staging block
#define NBLK (RNN_T / DEPTH)  // 256

#define SCALE 2.8853900817779268f   // 2*log2(e)

__global__ __launch_bounds__(BLOCK, 2) void vanilla_rnn_kernel(
    const float* __restrict__ x,     // [B,T,3]
    const float* __restrict__ W_ih,  // [32,3]
    const float* __restrict__ b_ih,  // [32]
    const float* __restrict__ W_hh,  // [32,32]
    const float* __restrict__ b_hh,  // [32]
    const float* __restrict__ W_fc,  // [2,32]
    const float* __restrict__ b_fc,  // [2]
    float* __restrict__ out,         // [B,T,32]
    float* __restrict__ hn_out)      // [B,2]
{
    const int tid  = threadIdx.x;
    const int lane = tid & 63;
    const int wv   = tid >> 6;         // wave within block (0..3)
    const int q    = lane >> 5;        // batch within wave (0..1)
    const int j    = lane & 31;        // owned output index
    const int g    = wv * 2 + q;       // group within block (0..7)
    const int b    = blockIdx.x * GROUPS + g;

    __shared__ float hs[GROUPS][32];                   // epilogue only
    __shared__ __align__(16) _Float16 hbuf[GROUPS][32]; // h state, f16
    __shared__ __align__(16) float xs4[4][2][2][12];   // [wave][slot][q][12]

    // loader role: lanes 0..23 of each wave stream 1 dword per block
    const bool loader = lane < 24;
    const int  lg     = lane / 12;     // batch-in-wave it loads for
    const int  fr     = lane % 12;     // float index within 12-float block
    const float* lsrc = x + (size_t)(blockIdx.x * GROUPS + wv * 2 + lg) * (RNN_T * 3) + fr;

    // W_hh row j as natural-order pairs (k=2q,2q+1), pre-scaled, f16.
    h2 W2[16];
#pragma unroll
    for (int m = 0; m < 16; ++m) {
        W2[m].x = (_Float16)(W_hh[j * 32 + 2 * m]     * SCALE);
        W2[m].y = (_Float16)(W_hh[j * 32 + 2 * m + 1] * SCALE);
    }

    // x-projection constants for own j, pre-scaled (f32)
    const float wi0 = W_ih[j * 3 + 0] * SCALE;
    const float wi1 = W_ih[j * 3 + 1] * SCALE;
    const float wi2 = W_ih[j * 3 + 2] * SCALE;
    const float bs  = (b_ih[j] + b_hh[j]) * SCALE;

    float* ob = out + (size_t)b * RNN_T * RNN_H;

    // init h state (wave-internal: same wave writes & reads)
    hbuf[g][j] = (_Float16)0.0f;

    // prologue: slots <- blocks 0,1; regs <- blocks 2,3 (all wave-internal)
    float xregA = 0.0f, xregB = 0.0f;
    if (loader) {
        const float d0 = lsrc[0];
        const float d1 = lsrc[12];
        xregA = lsrc[24];
        xregB = lsrc[36];
        xs4[wv][0][lg][fr] = d0;
        xs4[wv][1][lg][fr] = d1;
    }

    float hj = 0.0f;   // own h[j] in f32 (for epilogue)

#define BLOCK_BODY(SLOT, XREG, KB)                                            \
    {                                                                         \
        const float4* sp = reinterpret_cast<const float4*>(&xs4[wv][SLOT][q][0]); \
        const float4 xq0 = sp[0];                                             \
        const float4 xq1 = sp[1];                                             \
        const float4 xq2 = sp[2];                                             \
        if (loader) {                                                         \
            xs4[wv][SLOT][lg][fr] = XREG;          /* data for KB+2 */        \
            const int kf = ((KB) + 4 < NBLK) ? (KB) + 4 : NBLK - 1;           \
            XREG = lsrc[(size_t)kf * 12];          /* data for KB+4 */        \
        }                                                                     \
        __builtin_amdgcn_sched_barrier(0);                                    \
        const float xv[12] = {xq0.x, xq0.y, xq0.z, xq0.w,                     \
                              xq1.x, xq1.y, xq1.z, xq1.w,                     \
                              xq2.x, xq2.y, xq2.z, xq2.w};                    \
        /* per-block x-projection precompute for own j (h-independent) */     \
        float xp[DEPTH];                                                      \
        _Pragma("unroll")                                                     \
        for (int d = 0; d < DEPTH; ++d) {                                     \
            float v = fmaf(wi0, xv[d*3+0], bs);                               \
            v = fmaf(wi1, xv[d*3+1], v);                                      \
            v = fmaf(wi2, xv[d*3+2], v);                                      \
            xp[d] = v;                                                        \
        }                                                                     \
        _Pragma("unroll")                                                     \
        for (int d = 0; d < DEPTH; ++d) {                                     \
            /* broadcast-read ALL 32 h (16 h2) : 4x ds_read_b128 */           \
            const uint4* hb = reinterpret_cast<const uint4*>(&hbuf[g][0]);    \
            const uint4 c0 = hb[0];                                           \
            const uint4 c1 = hb[1];                                           \
            float a0 = xp[d], a1 = 0.0f;                                      \
            a0 = __builtin_amdgcn_fdot2(__builtin_bit_cast(h2, c0.x), W2[0],  a0, false); \
            a1 = __builtin_amdgcn_fdot2(__builtin_bit_cast(h2, c0.y), W2[1],  a1, false); \
            a0 = __builtin_amdgcn_fdot2(__builtin_bit_cast(h2, c0.z), W2[2],  a0, false); \
            a1 = __builtin_amdgcn_fdot2(__builtin_bit_cast(h2, c0.w), W2[3],  a1, false); \
            a0 = __builtin_amdgcn_fdot2(__builtin_bit_cast(h2, c1.x), W2[4],  a0, false); \
            a1 = __builtin_amdgcn_fdot2(__builtin_bit_cast(h2, c1.y), W2[5],  a1, false); \
            a0 = __builtin_amdgcn_fdot2(__builtin_bit_cast(h2, c1.z), W2[6],  a0, false); \
            a1 = __builtin_amdgcn_fdot2(__builtin_bit_cast(h2, c1.w), W2[7],  a1, false); \
            const uint4 c2 = hb[2];                                           \
            const uint4 c3 = hb[3];                                           \
            a0 = __builtin_amdgcn_fdot2(__builtin_bit_cast(h2, c2.x), W2[8],  a0, false); \
            a1 = __builtin_amdgcn_fdot2(__builtin_bit_cast(h2, c2.y), W2[9],  a1, false); \
            a0 = __builtin_amdgcn_fdot2(__builtin_bit_cast(h2, c2.z), W2[10], a0, false); \
            a1 = __builtin_amdgcn_fdot2(__builtin_bit_cast(h2, c2.w), W2[11], a1, false); \
            a0 = __builtin_amdgcn_fdot2(__builtin_bit_cast(h2, c3.x), W2[12], a0, false); \
            a1 = __builtin_amdgcn_fdot2(__builtin_bit_cast(h2, c3.y), W2[13], a1, false); \
            a0 = __builtin_amdgcn_fdot2(__builtin_bit_cast(h2, c3.z), W2[14], a0, false); \
            a1 = __builtin_amdgcn_fdot2(__builtin_bit_cast(h2, c3.w), W2[15], a1, false); \
            const float y = a0 + a1;                                          \
            /* tanh(z) = 1 - 2/(exp2(2*log2e*z)+1); inf-safe */               \
            const float th = fmaf(-2.0f, __builtin_amdgcn_rcpf(exp2f(y) + 1.0f), 1.0f); \
            __builtin_nontemporal_store(th, &ob[(size_t)((KB) * DEPTH + d) * RNN_H + j]); \
            hbuf[g][j] = (_Float16)th;   /* same-wave DS order -> next read */ \
            hj = th;                                                          \
        }                                                                     \
    }

    for (int k = 0; k < NBLK; k += 2) {
        BLOCK_BODY(0, xregA, k)
        BLOCK_BODY(1, xregB, k + 1)
    }

#undef BLOCK_BODY

    // h_n = h_T @ W_fc^T + b_fc  (batch's 32 lanes are wave-internal)
    hs[g][j] = hj;
    if (j < 2) {
        float acc = b_fc[j];
#pragma unroll
        for (int k = 0; k < 32; ++k) acc = fmaf(W_fc[j * 32 + k], hs[g][k], acc);
        hn_out[(size_t)b * 2 + j] = acc;
    }
}

extern "C" void kernel_launch(void* const* d_in, const int* in_sizes, int n_in,
                              void* d_out, int out_size, void* d_ws, size_t ws_size,
                              hipStream_t stream) {
    const float* x    = (const float*)d_in[0];
    const float* W_ih = (const float*)d_in[1];
    const float* b_ih = (const float*)d_in[2];
    const float* W_hh = (const float*)d_in[3];
    const float* b_hh = (const float*)d_in[4];
    const float* W_fc = (const float*)d_in[5];
    const float* b_fc = (const float*)d_in[6];

    float* out    = (float*)d_out;                                   // [B,T,H]
    float* hn_out = out + (size_t)RNN_B * RNN_T * RNN_H;             // [B,2]

    const int grid = RNN_B / GROUPS;  // 512 blocks = 2048 full waves = 2/SIMD
    vanilla_rnn_kernel<<<grid, BLOCK, 0, stream>>>(
        x, W_ih, b_ih, W_hh, b_hh, W_fc, b_fc, out, hn_out);
}